// Round 15
// baseline (266.143 us; speedup 1.0000x reference)
//
#include <hip/hip_runtime.h>

#define T_TOK 16384
#define H_DIM 4096
#define O_DIM 4096
#define NA 8
#define RANK 16
#define CHUNK 256            // f32 cols staged per chunk (shrink)
#define LROW 260             // padded LDS row stride
#define NCH (H_DIM / CHUNK)  // 16 chunks
#define NPE 32               // tokens per expand unit
#define MAXFLAGS 1040

typedef float f32x4 __attribute__((ext_vector_type(4)));
typedef short bf16x8 __attribute__((ext_vector_type(8)));

struct ushort4s { unsigned short x, y, z, w; };

static __device__ __forceinline__ unsigned short f2bf(float f) {
    unsigned int u = __float_as_uint(f);
    u = (u + 0x7fffu + ((u >> 16) & 1u)) >> 16;
    return (unsigned short)u;
}
static __device__ __forceinline__ float bf2f(unsigned short s) {
    return __uint_as_float(((unsigned int)s) << 16);
}

#define GL2LDS(gsrc, ldst)                                                   \
    __builtin_amdgcn_global_load_lds(                                        \
        (const __attribute__((address_space(1))) unsigned int*)(gsrc),       \
        (__attribute__((address_space(3))) unsigned int*)(ldst), 16, 0, 0)

// ---------------- setup: hist + prefix + bases + flag/work reset ----------------

__global__ void k_setup(const int* __restrict__ idx, int* __restrict__ counts,
                        int* __restrict__ offs, int* __restrict__ cursor,
                        int* __restrict__ tile_base, int* __restrict__ chunk_base,
                        int* __restrict__ work, int* __restrict__ flags) {
    __shared__ int h[NA];
    if (threadIdx.x < NA) h[threadIdx.x] = 0;
    __syncthreads();
    for (int i = threadIdx.x; i < T_TOK; i += 256)
        atomicAdd(&h[idx[i]], 1);
    __syncthreads();
    if (threadIdx.x == 0) {
        int run = 0, tb = 0, cb = 0;
        for (int n = 0; n < NA; ++n) {
            counts[n] = h[n]; offs[n] = run; cursor[n] = run; run += h[n];
            tile_base[n] = tb;  tb += (h[n] + 15) >> 4;
            chunk_base[n] = cb; cb += (h[n] + NPE - 1) / NPE;
        }
        tile_base[NA] = tb;
        chunk_base[NA] = cb;
        work[0] = 0;
    }
    for (int i = threadIdx.x; i < MAXFLAGS; i += 256) flags[i] = 0;
}

__global__ void k_scatter(const int* __restrict__ idx, int* __restrict__ cursor,
                          int* __restrict__ order) {
    int t = blockIdx.x * blockDim.x + threadIdx.x;
    int a = idx[t];
    int lane = threadIdx.x & 63;
    for (int n = 0; n < NA; n++) {
        unsigned long long m = __ballot(a == n);
        if (m) {
            int leader = __ffsll((unsigned long long)m) - 1;
            int cnt = __popcll(m);
            int base = 0;
            if (lane == leader) base = atomicAdd(&cursor[n], cnt);
            base = __shfl(base, leader);
            if (a == n) {
                int rank = __popcll(m & ((1ull << lane) - 1ull));
                order[base + rank] = t;
            }
        }
    }
}

// ---------------- transpose A -> ATb[n][r][h] (bf16) ----------------

__global__ void k_transpose(const float* __restrict__ A, unsigned short* __restrict__ ATb) {
    const int n = blockIdx.y;
    const int h0 = blockIdx.x * 256;
    __shared__ float lds[256 * 17];
    const float4* src = (const float4*)(A + ((size_t)n * H_DIM + h0) * RANK);
#pragma unroll
    for (int k = 0; k < 4; ++k) {
        int f = k * 256 + threadIdx.x;
        float4 v = src[f];
        int row = (f * 4) >> 4, col = (f * 4) & 15;
        lds[row * 17 + col + 0] = v.x;
        lds[row * 17 + col + 1] = v.y;
        lds[row * 17 + col + 2] = v.z;
        lds[row * 17 + col + 3] = v.w;
    }
    __syncthreads();
    unsigned short* dst = ATb + (size_t)n * RANK * H_DIM;
#pragma unroll
    for (int r = 0; r < RANK; ++r)
        dst[(size_t)r * H_DIM + h0 + threadIdx.x] = f2bf(lds[threadIdx.x * 17 + r]);
}

// ---------------- mega: ticket queue; shrink tiles then expand units ----------------
// Ticket t < n_shrink: 16-token MFMA shrink tile -> V + release flag.
// Else: expand unit (32 tokens x 1024-col quarter); spins on its 2 tile flags.
// Deadlock-free: producers never wait; any needed producer ticket was grabbed
// earlier by a running block. LDS union: shrink xs/vp (37.4 KB) vs expand
// blds/vlds/olds (34.9 KB).

__global__ __launch_bounds__(256, 3) void k_mega(
    const float* __restrict__ result, const float* __restrict__ x,
    const unsigned short* __restrict__ atb, const float* __restrict__ lora_b,
    const int* __restrict__ order, const int* __restrict__ counts,
    const int* __restrict__ offs, const int* __restrict__ tile_base,
    const int* __restrict__ chunk_base, int* __restrict__ work,
    int* __restrict__ flags, float* __restrict__ V, float* __restrict__ out) {

    __shared__ __align__(16) char un[37376];
    __shared__ int ticket_s;

    float (*xs)[16][LROW] = reinterpret_cast<float (*)[16][LROW]>(un);
    float (*vp)[16][16]   = reinterpret_cast<float (*)[16][16]>(un + 33280);
    unsigned short (*blds)[1024] = reinterpret_cast<unsigned short (*)[1024]>(un);
    float* vlds = reinterpret_cast<float*>(un + 32768);
    int*   olds = reinterpret_cast<int*>(un + 32768 + 2048);

    const int tid = threadIdx.x;
    const int w = tid >> 6, lane = tid & 63;
    const int mi = lane & 15, kg = lane >> 4;

    const int n_shrink = tile_base[NA];
    const int n_total  = n_shrink + chunk_base[NA] * 4;

    for (;;) {
        __syncthreads();
        if (tid == 0) ticket_s = atomicAdd(work, 1);
        __syncthreads();
        const int t = ticket_s;
        if (t >= n_total) return;

        if (t < n_shrink) {
            // ---------- shrink tile ----------
            int n = 0;
#pragma unroll
            for (int i = 1; i < NA; ++i) n += (t >= tile_base[i]);
            const int tile = t - tile_base[n];
            const int cnt = counts[n];
            const int seg = offs[n];
            const int tbase = tile << 4;
            const int np = min(16, cnt - tbase);

            int tok_i[4];
#pragma unroll
            for (int i = 0; i < 4; ++i)
                tok_i[i] = order[seg + min(tbase + w * 4 + i, cnt - 1)];

            const unsigned short* bp0 = atb + ((size_t)n * RANK + mi) * H_DIM + kg * 8;

#define STAGE(c_, b_)                                                         \
    {                                                                         \
        _Pragma("unroll") for (int i_ = 0; i_ < 4; ++i_) {                    \
            const int rr_ = w * 4 + i_;                                       \
            const float* src_ =                                               \
                x + (size_t)tok_i[i_] * H_DIM + (c_) * CHUNK + (lane << 2);   \
            GL2LDS(src_, &xs[b_][rr_][0]);                                    \
        }                                                                     \
    }
            f32x4 acc = {0.f, 0.f, 0.f, 0.f};
            STAGE(0, 0);
            __syncthreads();
            for (int c = 0; c < NCH; ++c) {
                if (c + 1 < NCH) STAGE(c + 1, (c + 1) & 1);
                const int b = c & 1;
                const int cb = w * 64;
#pragma unroll
                for (int ks = 0; ks < 2; ++ks) {
                    const float* lsrc = &xs[b][mi][cb + ks * 32 + kg * 8];
                    f32x4 xlo = *(const f32x4*)lsrc;
                    f32x4 xhi = *(const f32x4*)(lsrc + 4);
                    bf16x8 bfrag = *(const bf16x8*)(bp0 + (size_t)c * CHUNK + cb + ks * 32);
                    bf16x8 afrag;
                    afrag[0] = (short)f2bf(xlo.x); afrag[1] = (short)f2bf(xlo.y);
                    afrag[2] = (short)f2bf(xlo.z); afrag[3] = (short)f2bf(xlo.w);
                    afrag[4] = (short)f2bf(xhi.x); afrag[5] = (short)f2bf(xhi.y);
                    afrag[6] = (short)f2bf(xhi.z); afrag[7] = (short)f2bf(xhi.w);
                    acc = __builtin_amdgcn_mfma_f32_16x16x32_bf16(afrag, bfrag, acc, 0, 0, 0);
                }
                __syncthreads();
            }
#undef STAGE
#pragma unroll
            for (int q = 0; q < 4; ++q)
                vp[w][kg * 4 + q][mi] = acc[q];
            __syncthreads();
            {
                const int p = tid >> 4, r = tid & 15;
                if (p < np) {
                    float s = (vp[0][p][r] + vp[1][p][r]) + (vp[2][p][r] + vp[3][p][r]);
                    V[(size_t)(seg + tbase + p) * RANK + r] = s;
                }
            }
            __syncthreads();               // drain all V stores (vmcnt 0)
            if (tid == 0) {
                __threadfence();           // device-scope release
                atomicExch(&flags[t], 1);
            }
        } else {
            // ---------- expand unit ----------
            const int u = t - n_shrink;
            const int q = u & 3;
            const int c = u >> 2;
            int n = 0;
#pragma unroll
            for (int i = 1; i < NA; ++i) n += (c >= chunk_base[i]);
            const int tc = c - chunk_base[n];
            const int cnt = counts[n];
            const int seg = offs[n];
            const int pbase = tc * NPE;
            const int np = min(NPE, cnt - pbase);
            const int ntiles = tile_base[n + 1] - tile_base[n];

            if (tid == 0) {
                const int f0 = tile_base[n] + tc * 2;
                while (atomicAdd(&flags[f0], 0) == 0) __builtin_amdgcn_s_sleep(2);
                if (tc * 2 + 1 < ntiles)
                    while (atomicAdd(&flags[f0 + 1], 0) == 0) __builtin_amdgcn_s_sleep(2);
            }
            __syncthreads();

            const int oq = q * 1024;
            const int o0 = oq + (tid << 2);

            const float* Bn = lora_b + (size_t)n * RANK * O_DIM + oq;
#pragma unroll
            for (int r = 0; r < RANK; ++r) {
                f32x4 v = *(const f32x4*)(Bn + (size_t)r * O_DIM + (tid << 2));
                ushort4s uu;
                uu.x = f2bf(v.x); uu.y = f2bf(v.y); uu.z = f2bf(v.z); uu.w = f2bf(v.w);
                *(ushort4s*)&blds[r][tid << 2] = uu;
            }
            // V via sc0 (L1-bypass) scalar loads
            for (int i = tid; i < np * RANK; i += 256) {
                volatile const float* vv = V + (size_t)(seg + pbase) * RANK + i;
                vlds[i] = *vv;
            }
            if (tid < np) olds[tid] = order[seg + pbase + tid];
            __syncthreads();

            size_t offA = (size_t)olds[0] * O_DIM + o0;
            f32x4 rA = __builtin_nontemporal_load((const f32x4*)(result + offA));
            size_t offB = offA, offC = offA;
            f32x4 rB = rA, rC = rA;
            if (np > 1) {
                offB = (size_t)olds[1] * O_DIM + o0;
                rB = __builtin_nontemporal_load((const f32x4*)(result + offB));
            }
            if (np > 2) {
                offC = (size_t)olds[2] * O_DIM + o0;
                rC = __builtin_nontemporal_load((const f32x4*)(result + offC));
            }
            for (int p = 0; p < np; ++p) {
                f32x4 rD = rC;
                size_t offD = 0;
                if (p + 3 < np) {
                    offD = (size_t)olds[p + 3] * O_DIM + o0;
                    rD = __builtin_nontemporal_load((const f32x4*)(result + offD));
                }
                float va[RANK];
#pragma unroll
                for (int uu = 0; uu < 4; ++uu)
                    *(f32x4*)&va[uu * 4] = *(const f32x4*)&vlds[p * RANK + uu * 4];
                f32x4 acc2 = rA;
#pragma unroll
                for (int r = 0; r < RANK; ++r) {
                    ushort4s uu = *(const ushort4s*)&blds[r][tid << 2];
                    acc2.x = fmaf(va[r], bf2f(uu.x), acc2.x);
                    acc2.y = fmaf(va[r], bf2f(uu.y), acc2.y);
                    acc2.z = fmaf(va[r], bf2f(uu.z), acc2.z);
                    acc2.w = fmaf(va[r], bf2f(uu.w), acc2.w);
                }
                __builtin_nontemporal_store(acc2, (f32x4*)(out + offA));
                rA = rB; offA = offB;
                rB = rC; offB = offC;
                rC = rD; offC = offD;
            }
        }
    }
}

// ---------------- launch ----------------

extern "C" void kernel_launch(void* const* d_in, const int* in_sizes, int n_in,
                              void* d_out, int out_size, void* d_ws, size_t ws_size,
                              hipStream_t stream) {
    const float* result = (const float*)d_in[0];
    const float* x      = (const float*)d_in[1];
    const float* lora_a = (const float*)d_in[2];
    const float* lora_b = (const float*)d_in[3];
    const int*   aidx   = (const int*)d_in[4];
    float* out = (float*)d_out;

    float* V        = (float*)d_ws;                 // 1 MB
    int* order      = (int*)(V + (size_t)T_TOK * RANK);
    int* counts     = order + T_TOK;
    int* offs       = counts + NA;
    int* cursor     = offs + NA;
    int* tile_base  = cursor + NA;                  // 9
    int* chunk_base = tile_base + 9;                // 9
    int* work       = chunk_base + 9;               // 1 (+pad 6)
    int* flags      = work + 7;                     // MAXFLAGS
    unsigned short* ATb = (unsigned short*)(flags + MAXFLAGS);   // 1 MB

    k_setup<<<dim3(1), dim3(256), 0, stream>>>(aidx, counts, offs, cursor,
                                               tile_base, chunk_base, work, flags);
    k_scatter<<<dim3(64), dim3(256), 0, stream>>>(aidx, cursor, order);
    k_transpose<<<dim3(16, NA), dim3(256), 0, stream>>>(lora_a, ATb);
    k_mega<<<dim3(1024), dim3(256), 0, stream>>>(
        result, x, ATb, lora_b, order, counts, offs,
        tile_base, chunk_base, work, flags, V, out);
}

// Round 16
// 255.436 us; speedup vs baseline: 1.0419x; 1.0419x over previous
//
#include <hip/hip_runtime.h>

#define T_TOK 16384
#define H_DIM 4096
#define O_DIM 4096
#define NA 8
#define RANK 16
#define CHUNK 256            // f32 cols staged per chunk (shrink)
#define LROW 260             // padded LDS row stride
#define NCH (H_DIM / CHUNK)  // 16 chunks
#define NPE 64               // tokens per expand block

typedef float f32x4 __attribute__((ext_vector_type(4)));
typedef float f32x2 __attribute__((ext_vector_type(2)));
typedef short bf16x8 __attribute__((ext_vector_type(8)));

static __device__ __forceinline__ unsigned short f2bf(float f) {
    unsigned int u = __float_as_uint(f);
    u = (u + 0x7fffu + ((u >> 16) & 1u)) >> 16;
    return (unsigned short)u;
}

#define GL2LDS(gsrc, ldst)                                                   \
    __builtin_amdgcn_global_load_lds(                                        \
        (const __attribute__((address_space(1))) unsigned int*)(gsrc),       \
        (__attribute__((address_space(3))) unsigned int*)(ldst), 16, 0, 0)

// ---------------- setup: zero + hist + prefix in ONE kernel ----------------

__global__ void k_setup(const int* __restrict__ idx, int* __restrict__ counts,
                        int* __restrict__ offs, int* __restrict__ cursor) {
    __shared__ int h[NA];
    if (threadIdx.x < NA) h[threadIdx.x] = 0;
    __syncthreads();
    for (int i = threadIdx.x; i < T_TOK; i += 256)
        atomicAdd(&h[idx[i]], 1);
    __syncthreads();
    if (threadIdx.x == 0) {
        int run = 0;
        for (int n = 0; n < NA; ++n) {
            counts[n] = h[n]; offs[n] = run; cursor[n] = run; run += h[n];
        }
    }
}

__global__ void k_scatter(const int* __restrict__ idx, int* __restrict__ cursor,
                          int* __restrict__ order) {
    int t = blockIdx.x * blockDim.x + threadIdx.x;
    int a = idx[t];
    int lane = threadIdx.x & 63;
    for (int n = 0; n < NA; n++) {
        unsigned long long m = __ballot(a == n);
        if (m) {
            int leader = __ffsll((unsigned long long)m) - 1;
            int cnt = __popcll(m);
            int base = 0;
            if (lane == leader) base = atomicAdd(&cursor[n], cnt);
            base = __shfl(base, leader);
            if (a == n) {
                int rank = __popcll(m & ((1ull << lane) - 1ull));
                order[base + rank] = t;
            }
        }
    }
}

// ---------------- transpose A -> ATb[n][r][h] (bf16) ----------------

__global__ void k_transpose(const float* __restrict__ A, unsigned short* __restrict__ ATb) {
    const int n = blockIdx.y;
    const int h0 = blockIdx.x * 256;
    __shared__ float lds[256 * 17];
    const float4* src = (const float4*)(A + ((size_t)n * H_DIM + h0) * RANK);
#pragma unroll
    for (int k = 0; k < 4; ++k) {
        int f = k * 256 + threadIdx.x;
        float4 v = src[f];
        int row = (f * 4) >> 4, col = (f * 4) & 15;
        lds[row * 17 + col + 0] = v.x;
        lds[row * 17 + col + 1] = v.y;
        lds[row * 17 + col + 2] = v.z;
        lds[row * 17 + col + 3] = v.w;
    }
    __syncthreads();
    unsigned short* dst = ATb + (size_t)n * RANK * H_DIM;
#pragma unroll
    for (int r = 0; r < RANK; ++r)
        dst[(size_t)r * H_DIM + h0 + threadIdx.x] = f2bf(lds[threadIdx.x * 17 + r]);
}

// ---------------- shrink: async-staged MFMA tile, writes V[T][16] (r11 form) ----------------

__global__ __launch_bounds__(256, 4) void k_shrink(
    const float* __restrict__ x, const unsigned short* __restrict__ atb,
    const int* __restrict__ order, const int* __restrict__ counts,
    const int* __restrict__ offs, float* __restrict__ V) {

    const int bid = blockIdx.x;
    int n = 0, tile = 0, found = 0, acc_t = 0;
#pragma unroll
    for (int i = 0; i < NA; ++i) {
        int tn = (counts[i] + 15) >> 4;
        if (!found && bid < acc_t + tn) { n = i; tile = bid - acc_t; found = 1; }
        acc_t += tn;
    }
    if (!found) return;
    const int cnt = counts[n];
    const int seg = offs[n];
    const int tbase = tile << 4;
    const int np = min(16, cnt - tbase);

    __shared__ float xs[2][16][LROW];    // 33.3 KB
    __shared__ float vp[4][16][16];      // 4 KB

    const int w = threadIdx.x >> 6, lane = threadIdx.x & 63;
    const int mi = lane & 15, kg = lane >> 4;

    int tok_i[4];
#pragma unroll
    for (int i = 0; i < 4; ++i)
        tok_i[i] = order[seg + min(tbase + w * 4 + i, cnt - 1)];

    const unsigned short* bp0 = atb + ((size_t)n * RANK + mi) * H_DIM + kg * 8;

#define STAGE(c_, b_)                                                         \
    {                                                                         \
        _Pragma("unroll") for (int i_ = 0; i_ < 4; ++i_) {                    \
            const int rr_ = w * 4 + i_;                                       \
            const float* src_ =                                               \
                x + (size_t)tok_i[i_] * H_DIM + (c_) * CHUNK + (lane << 2);   \
            GL2LDS(src_, &xs[b_][rr_][0]);                                    \
        }                                                                     \
    }

    f32x4 acc = {0.f, 0.f, 0.f, 0.f};

    STAGE(0, 0);
    __syncthreads();
    for (int c = 0; c < NCH; ++c) {
        if (c + 1 < NCH) STAGE(c + 1, (c + 1) & 1);
        const int b = c & 1;
        const int cb = w * 64;
#pragma unroll
        for (int ks = 0; ks < 2; ++ks) {
            const float* lsrc = &xs[b][mi][cb + ks * 32 + kg * 8];
            f32x4 xlo = *(const f32x4*)lsrc;
            f32x4 xhi = *(const f32x4*)(lsrc + 4);
            bf16x8 bfrag = *(const bf16x8*)(bp0 + (size_t)c * CHUNK + cb + ks * 32);
            bf16x8 afrag;
            afrag[0] = (short)f2bf(xlo.x); afrag[1] = (short)f2bf(xlo.y);
            afrag[2] = (short)f2bf(xlo.z); afrag[3] = (short)f2bf(xlo.w);
            afrag[4] = (short)f2bf(xhi.x); afrag[5] = (short)f2bf(xhi.y);
            afrag[6] = (short)f2bf(xhi.z); afrag[7] = (short)f2bf(xhi.w);
            acc = __builtin_amdgcn_mfma_f32_16x16x32_bf16(afrag, bfrag, acc, 0, 0, 0);
        }
        __syncthreads();
    }
#undef STAGE

#pragma unroll
    for (int q = 0; q < 4; ++q)
        vp[w][kg * 4 + q][mi] = acc[q];
    __syncthreads();
    {
        const int p = threadIdx.x >> 4, r = threadIdx.x & 15;
        if (p < np) {
            float s = (vp[0][p][r] + vp[1][p][r]) + (vp[2][p][r] + vp[3][p][r]);
            V[(size_t)(seg + tbase + p) * RANK + r] = s;
        }
    }
}

// ---------------- expand: out[t] = result[t] + V[t] @ B[n] ----------------
// grid (8, 256, 8), block 256, NPE=64. Thread owns 2 cols -> B slice = 16 x f32x2
// = 32 VGPR, register-resident, f32 (no conversion, no B LDS traffic). va via
// broadcast ds_read_b128. 4-deep rotation, plain result loads (L3), NT store.

__global__ __launch_bounds__(256, 4) void k_expand(
    const float* __restrict__ result, const float* __restrict__ lora_b,
    const float* __restrict__ V, const int* __restrict__ order,
    const int* __restrict__ counts, const int* __restrict__ offs,
    float* __restrict__ out) {
    const int n = blockIdx.z;
    const int cnt = counts[n];
    const int pbase = blockIdx.y * NPE;
    if (pbase >= cnt) return;
    const int seg = offs[n];
    const int o0 = blockIdx.x * 512 + (threadIdx.x << 1);

    __shared__ float vlds[NPE * RANK];            // 4 KB
    __shared__ int olds[NPE];

    const int np = min(NPE, cnt - pbase);

    if (threadIdx.x < np * 4)
        ((f32x4*)vlds)[threadIdx.x] =
            ((const f32x4*)V)[(size_t)(seg + pbase) * 4 + threadIdx.x];
    if (threadIdx.x < np) olds[threadIdx.x] = order[seg + pbase + threadIdx.x];

    // B slice: 16 x f32x2 in registers, f32 (L2-hot)
    f32x2 b[RANK];
    const float* Bn = lora_b + (size_t)n * RANK * O_DIM + o0;
#pragma unroll
    for (int r = 0; r < RANK; ++r)
        b[r] = *(const f32x2*)(Bn + (size_t)r * O_DIM);

    __syncthreads();

    // 4-deep rotation on result rows (32-bit element offsets)
    unsigned offA = (unsigned)olds[0] * O_DIM + o0;
    f32x2 rA = *(const f32x2*)(result + offA);
    unsigned offB = offA, offC = offA, offD = offA;
    f32x2 rB = rA, rC = rA, rD = rA;
    if (np > 1) { offB = (unsigned)olds[1] * O_DIM + o0; rB = *(const f32x2*)(result + offB); }
    if (np > 2) { offC = (unsigned)olds[2] * O_DIM + o0; rC = *(const f32x2*)(result + offC); }
    if (np > 3) { offD = (unsigned)olds[3] * O_DIM + o0; rD = *(const f32x2*)(result + offD); }

    for (int p = 0; p < np; ++p) {
        f32x2 rE = rD;
        unsigned offE = 0;
        if (p + 4 < np) {
            offE = (unsigned)olds[p + 4] * O_DIM + o0;
            rE = *(const f32x2*)(result + offE);
        }
        f32x2 acc = rA;
#pragma unroll
        for (int q = 0; q < 4; ++q) {
            f32x4 va = *(const f32x4*)&vlds[p * RANK + q * 4];   // broadcast read
            acc.x = fmaf(va.x, b[q * 4 + 0].x, acc.x);
            acc.y = fmaf(va.x, b[q * 4 + 0].y, acc.y);
            acc.x = fmaf(va.y, b[q * 4 + 1].x, acc.x);
            acc.y = fmaf(va.y, b[q * 4 + 1].y, acc.y);
            acc.x = fmaf(va.z, b[q * 4 + 2].x, acc.x);
            acc.y = fmaf(va.z, b[q * 4 + 2].y, acc.y);
            acc.x = fmaf(va.w, b[q * 4 + 3].x, acc.x);
            acc.y = fmaf(va.w, b[q * 4 + 3].y, acc.y);
        }
        __builtin_nontemporal_store(acc, (f32x2*)(out + offA));
        rA = rB; offA = offB;
        rB = rC; offB = offC;
        rC = rD; offC = offD;
        rD = rE; offD = offE;
    }
}

// ---------------- launch ----------------

extern "C" void kernel_launch(void* const* d_in, const int* in_sizes, int n_in,
                              void* d_out, int out_size, void* d_ws, size_t ws_size,
                              hipStream_t stream) {
    const float* result = (const float*)d_in[0];
    const float* x      = (const float*)d_in[1];
    const float* lora_a = (const float*)d_in[2];
    const float* lora_b = (const float*)d_in[3];
    const int*   aidx   = (const int*)d_in[4];
    float* out = (float*)d_out;

    float* V    = (float*)d_ws;                                  // 1 MB
    int* order  = (int*)((char*)d_ws + (size_t)T_TOK * RANK * 4);
    int* counts = order + T_TOK;
    int* offs   = counts + NA;
    int* cursor = offs + NA;
    unsigned short* ATb = (unsigned short*)(cursor + NA);        // 1 MB

    k_setup<<<dim3(1), dim3(256), 0, stream>>>(aidx, counts, offs, cursor);
    k_scatter<<<dim3(64), dim3(256), 0, stream>>>(aidx, cursor, order);
    k_transpose<<<dim3(16, NA), dim3(256), 0, stream>>>(lora_a, ATb);
    k_shrink<<<dim3(T_TOK / 16 + NA), dim3(256), 0, stream>>>(
        x, ATb, order, counts, offs, V);
    k_expand<<<dim3(8, 256, NA), dim3(256), 0, stream>>>(
        result, lora_b, V, order, counts, offs, out);
}

// Round 17
// 216.860 us; speedup vs baseline: 1.2273x; 1.1779x over previous
//
#include <hip/hip_runtime.h>

#define T_TOK 16384
#define H_DIM 4096
#define O_DIM 4096
#define NA 8
#define RANK 16
#define CHUNK 256            // f32 cols staged per chunk (shrink)
#define LROW 260             // padded LDS row stride
#define NCH (H_DIM / CHUNK)  // 16 chunks
#define NPE 64               // sequential tokens per expand block
#define OCW 128              // expand o-chunk width

typedef float f32x4 __attribute__((ext_vector_type(4)));
typedef short bf16x8 __attribute__((ext_vector_type(8)));

static __device__ __forceinline__ unsigned short f2bf(float f) {
    unsigned int u = __float_as_uint(f);
    u = (u + 0x7fffu + ((u >> 16) & 1u)) >> 16;
    return (unsigned short)u;
}
static __device__ __forceinline__ float bf2f_lo(unsigned int w) {
    return __uint_as_float(w << 16);
}
static __device__ __forceinline__ float bf2f_hi(unsigned int w) {
    return __uint_as_float(w & 0xffff0000u);
}

#define GL2LDS(gsrc, ldst)                                                   \
    __builtin_amdgcn_global_load_lds(                                        \
        (const __attribute__((address_space(1))) unsigned int*)(gsrc),       \
        (__attribute__((address_space(3))) unsigned int*)(ldst), 16, 0, 0)

// ---------------- setup: zero + hist + prefix in ONE kernel ----------------

__global__ void k_setup(const int* __restrict__ idx, int* __restrict__ counts,
                        int* __restrict__ offs, int* __restrict__ cursor) {
    __shared__ int h[NA];
    if (threadIdx.x < NA) h[threadIdx.x] = 0;
    __syncthreads();
    for (int i = threadIdx.x; i < T_TOK; i += 256)
        atomicAdd(&h[idx[i]], 1);
    __syncthreads();
    if (threadIdx.x == 0) {
        int run = 0;
        for (int n = 0; n < NA; ++n) {
            counts[n] = h[n]; offs[n] = run; cursor[n] = run; run += h[n];
        }
    }
}

__global__ void k_scatter(const int* __restrict__ idx, int* __restrict__ cursor,
                          int* __restrict__ order) {
    int t = blockIdx.x * blockDim.x + threadIdx.x;
    int a = idx[t];
    int lane = threadIdx.x & 63;
    for (int n = 0; n < NA; n++) {
        unsigned long long m = __ballot(a == n);
        if (m) {
            int leader = __ffsll((unsigned long long)m) - 1;
            int cnt = __popcll(m);
            int base = 0;
            if (lane == leader) base = atomicAdd(&cursor[n], cnt);
            base = __shfl(base, leader);
            if (a == n) {
                int rank = __popcll(m & ((1ull << lane) - 1ull));
                order[base + rank] = t;
            }
        }
    }
}

// ---------------- transpose A -> ATb[n][r][h] (bf16) ----------------

__global__ void k_transpose(const float* __restrict__ A, unsigned short* __restrict__ ATb) {
    const int n = blockIdx.y;
    const int h0 = blockIdx.x * 256;
    __shared__ float lds[256 * 17];
    const float4* src = (const float4*)(A + ((size_t)n * H_DIM + h0) * RANK);
#pragma unroll
    for (int k = 0; k < 4; ++k) {
        int f = k * 256 + threadIdx.x;
        float4 v = src[f];
        int row = (f * 4) >> 4, col = (f * 4) & 15;
        lds[row * 17 + col + 0] = v.x;
        lds[row * 17 + col + 1] = v.y;
        lds[row * 17 + col + 2] = v.z;
        lds[row * 17 + col + 3] = v.w;
    }
    __syncthreads();
    unsigned short* dst = ATb + (size_t)n * RANK * H_DIM;
#pragma unroll
    for (int r = 0; r < RANK; ++r)
        dst[(size_t)r * H_DIM + h0 + threadIdx.x] = f2bf(lds[threadIdx.x * 17 + r]);
}

// ---------------- convert B -> BTb[n][r][o] (bf16, same layout) ----------------

__global__ void k_convb(const float* __restrict__ B, unsigned short* __restrict__ BTb) {
    const size_t i = (size_t)blockIdx.x * 256 + threadIdx.x;   // f32x4 index
    f32x4 v = ((const f32x4*)B)[i];
    unsigned short u[4];
    u[0] = f2bf(v.x); u[1] = f2bf(v.y); u[2] = f2bf(v.z); u[3] = f2bf(v.w);
    ((unsigned long long*)BTb)[i] =
        (unsigned long long)u[0] | ((unsigned long long)u[1] << 16) |
        ((unsigned long long)u[2] << 32) | ((unsigned long long)u[3] << 48);
}

// ---------------- shrink: async-staged MFMA tile, scatter-writes V[tok][16] ----------------

__global__ __launch_bounds__(256, 4) void k_shrink(
    const float* __restrict__ x, const unsigned short* __restrict__ atb,
    const int* __restrict__ order, const int* __restrict__ counts,
    const int* __restrict__ offs, float* __restrict__ V) {

    const int bid = blockIdx.x;
    int n = 0, tile = 0, found = 0, acc_t = 0;
#pragma unroll
    for (int i = 0; i < NA; ++i) {
        int tn = (counts[i] + 15) >> 4;
        if (!found && bid < acc_t + tn) { n = i; tile = bid - acc_t; found = 1; }
        acc_t += tn;
    }
    if (!found) return;
    const int cnt = counts[n];
    const int seg = offs[n];
    const int tbase = tile << 4;
    const int np = min(16, cnt - tbase);

    __shared__ float xs[2][16][LROW];    // 33.3 KB
    __shared__ float vp[4][16][16];      // 4 KB

    const int w = threadIdx.x >> 6, lane = threadIdx.x & 63;
    const int mi = lane & 15, kg = lane >> 4;

    int tok_i[4];
#pragma unroll
    for (int i = 0; i < 4; ++i)
        tok_i[i] = order[seg + min(tbase + w * 4 + i, cnt - 1)];

    const unsigned short* bp0 = atb + ((size_t)n * RANK + mi) * H_DIM + kg * 8;

#define STAGE(c_, b_)                                                         \
    {                                                                         \
        _Pragma("unroll") for (int i_ = 0; i_ < 4; ++i_) {                    \
            const int rr_ = w * 4 + i_;                                       \
            const float* src_ =                                               \
                x + (size_t)tok_i[i_] * H_DIM + (c_) * CHUNK + (lane << 2);   \
            GL2LDS(src_, &xs[b_][rr_][0]);                                    \
        }                                                                     \
    }

    f32x4 acc = {0.f, 0.f, 0.f, 0.f};

    STAGE(0, 0);
    __syncthreads();
    for (int c = 0; c < NCH; ++c) {
        if (c + 1 < NCH) STAGE(c + 1, (c + 1) & 1);
        const int b = c & 1;
        const int cb = w * 64;
#pragma unroll
        for (int ks = 0; ks < 2; ++ks) {
            const float* lsrc = &xs[b][mi][cb + ks * 32 + kg * 8];
            f32x4 xlo = *(const f32x4*)lsrc;
            f32x4 xhi = *(const f32x4*)(lsrc + 4);
            bf16x8 bfrag = *(const bf16x8*)(bp0 + (size_t)c * CHUNK + cb + ks * 32);
            bf16x8 afrag;
            afrag[0] = (short)f2bf(xlo.x); afrag[1] = (short)f2bf(xlo.y);
            afrag[2] = (short)f2bf(xlo.z); afrag[3] = (short)f2bf(xlo.w);
            afrag[4] = (short)f2bf(xhi.x); afrag[5] = (short)f2bf(xhi.y);
            afrag[6] = (short)f2bf(xhi.z); afrag[7] = (short)f2bf(xhi.w);
            acc = __builtin_amdgcn_mfma_f32_16x16x32_bf16(afrag, bfrag, acc, 0, 0, 0);
        }
        __syncthreads();
    }
#undef STAGE

#pragma unroll
    for (int q = 0; q < 4; ++q)
        vp[w][kg * 4 + q][mi] = acc[q];
    __syncthreads();
    {
        const int p = threadIdx.x >> 4, r = threadIdx.x & 15;
        if (p < np) {
            float s = (vp[0][p][r] + vp[1][p][r]) + (vp[2][p][r] + vp[3][p][r]);
            const int tok = order[seg + tbase + p];
            V[(size_t)tok * RANK + r] = s;     // UNSORTED (natural token index)
        }
    }
}

// ---------------- expand: sequential tokens, all-adapter B chunk in LDS ----------------
// grid (32 o-chunks, 256), block 256. Block = 64 consecutive tokens x 128 cols.
// ball[8][16][128] bf16 (32 KB) staged once; V/aidx read sequentially; result
// streamed sequentially (plain loads, L3-friendly); out NT-stored sequentially.
// No `order` anywhere -> pure streaming on the 512 MB result/out traffic.

__global__ __launch_bounds__(256, 3) void k_expand(
    const float* __restrict__ result, const unsigned short* __restrict__ btb,
    const float* __restrict__ V, const int* __restrict__ aidx,
    float* __restrict__ out) {
    const int oc = blockIdx.x;
    const int t0 = blockIdx.y * NPE;
    const int tid = threadIdx.x;

    __shared__ unsigned short ball[NA][RANK][OCW];   // 32 KB
    __shared__ float vlds[NPE * RANK];               // 4 KB
    __shared__ int aseq[NPE];

    // stage all 8 adapters' B chunk (bf16, 8192 u32 words, 32/thread)
    {
        unsigned int* dst = (unsigned int*)ball;
#pragma unroll
        for (int k = 0; k < 32; ++k) {
            int wd = k * 256 + tid;
            int a = wd >> 10, r = (wd >> 6) & 15, c2 = wd & 63;
            const unsigned int* src = (const unsigned int*)
                (btb + (((size_t)a * RANK + r) * O_DIM + oc * OCW));
            dst[wd] = src[c2];
        }
    }
    // stage V (sequential 4 KB) and adapter ids
    for (int k = tid; k < NPE * 4; k += 256)
        ((f32x4*)vlds)[k] = ((const f32x4*)V)[(size_t)t0 * 4 + k];
    if (tid < NPE) aseq[tid] = aidx[t0 + tid];
    __syncthreads();

    const int g = tid >> 5, li = tid & 31;            // 8 row-groups x 32 lanes
    const int ocol = oc * OCW + li * 4;

    // 2-deep rotation on the sequential result stream
    int p0 = g;
    size_t offA = (size_t)(t0 + p0) * O_DIM + ocol;
    f32x4 rA = *(const f32x4*)(result + offA);

#pragma unroll 1
    for (int it = 0; it < NPE / 8; ++it) {
        const int p = it * 8 + g;
        f32x4 rB;
        size_t offB = 0;
        if (it + 1 < NPE / 8) {
            offB = (size_t)(t0 + p + 8) * O_DIM + ocol;
            rB = *(const f32x4*)(result + offB);
        }
        const int a = aseq[p];
        const unsigned short* brow = &ball[a][0][li * 4];
        f32x4 acc = rA;
#pragma unroll
        for (int r = 0; r < RANK; ++r) {
            float v = vlds[p * RANK + r];             // broadcast (conflict-free)
            unsigned long long bb = *(const unsigned long long*)(brow + (size_t)r * OCW);
            unsigned int blo = (unsigned int)bb, bhi = (unsigned int)(bb >> 32);
            acc.x = fmaf(v, bf2f_lo(blo), acc.x);
            acc.y = fmaf(v, bf2f_hi(blo), acc.y);
            acc.z = fmaf(v, bf2f_lo(bhi), acc.z);
            acc.w = fmaf(v, bf2f_hi(bhi), acc.w);
        }
        __builtin_nontemporal_store(acc, (f32x4*)(out + offA));
        rA = rB; offA = offB;
    }
}

// ---------------- launch ----------------

extern "C" void kernel_launch(void* const* d_in, const int* in_sizes, int n_in,
                              void* d_out, int out_size, void* d_ws, size_t ws_size,
                              hipStream_t stream) {
    const float* result = (const float*)d_in[0];
    const float* x      = (const float*)d_in[1];
    const float* lora_a = (const float*)d_in[2];
    const float* lora_b = (const float*)d_in[3];
    const int*   aidx   = (const int*)d_in[4];
    float* out = (float*)d_out;

    float* V    = (float*)d_ws;                                  // 1 MB (unsorted)
    int* order  = (int*)((char*)d_ws + (size_t)T_TOK * RANK * 4);
    int* counts = order + T_TOK;
    int* offs   = counts + NA;
    int* cursor = offs + NA;
    unsigned short* ATb = (unsigned short*)(cursor + NA);        // 1 MB
    unsigned short* BTb = ATb + (size_t)NA * RANK * H_DIM;       // 1 MB

    k_setup<<<dim3(1), dim3(256), 0, stream>>>(aidx, counts, offs, cursor);
    k_scatter<<<dim3(64), dim3(256), 0, stream>>>(aidx, cursor, order);
    k_transpose<<<dim3(16, NA), dim3(256), 0, stream>>>(lora_a, ATb);
    k_convb<<<dim3((NA * RANK * O_DIM / 4) / 256), dim3(256), 0, stream>>>(lora_b, BTb);
    k_shrink<<<dim3(T_TOK / 16 + NA), dim3(256), 0, stream>>>(
        x, ATb, order, counts, offs, V);
    k_expand<<<dim3(O_DIM / OCW, T_TOK / NPE), dim3(256), 0, stream>>>(
        result, BTb, V, aidx, out);
}